// Round 6
// baseline (115.910 us; speedup 1.0000x reference)
//
#include <hip/hip_runtime.h>

// MMD over persistence diagrams, RBF kernel, WIDTH=1, DECAY=1.
// out = sum_b weights[b]/ns[b]^2 * (S_XX - 2 S_XY + S_YY)
// S_AB = sum_{n,m} exp(-||a_n-b_m||^2) * wa_n * wb_m,
// points (birth,death)->(x=birth, l=death-birth), w = l.
//
// R6: v_exp_f32 (16cy trans, issue-blocking) replaced by packed-f32
// polynomial exp2: magic-const range reduction + deg-7 Taylor via
// v_pk_fma_f32 + bit-trick 2^n scale. m processed in pairs; LDS tiles
// are SoA so ds_read_b64 yields pre-packed operands. Prep kernel removed
// (blocks transform raw X/Y directly); atomics removed (private slot per
// block + deterministic finalize sum).

#define LOG2E_F  1.44269504088896340736f
#define SQRT2C_F 1.69864360213614f     // sqrt(2*log2(e))
#define MAGIC_F  12582912.0f           // 1.5 * 2^23

typedef float        v2f __attribute__((ext_vector_type(2)));
typedef unsigned int v2u __attribute__((ext_vector_type(2)));

#define TPB 256

__device__ __forceinline__ v2f fma2(v2f a, v2f b, v2f c) {
    return __builtin_elementwise_fma(a, b, c);
}
__device__ __forceinline__ v2f splat2(float x) { return (v2f){x, x}; }

// 2^t for t in ~[-126, +1], ~2e-7 rel err. All full-rate VALU (packable).
__device__ __forceinline__ v2f exp2_poly(v2f t) {
    const v2f MG = splat2(MAGIC_F);
    v2f z = t + MG;          // RNE -> round(t) encoded in mantissa
    v2f n = z - MG;          // exact
    v2f f = t - n;           // exact, in [-0.5, 0.5]
    v2f q = splat2(1.5252733e-5f);
    q = fma2(q, f, splat2(1.5403530e-4f));
    q = fma2(q, f, splat2(1.3333558e-3f));
    q = fma2(q, f, splat2(9.6181291e-3f));
    q = fma2(q, f, splat2(5.5504109e-2f));
    q = fma2(q, f, splat2(2.4022651e-1f));
    q = fma2(q, f, splat2(6.9314718e-1f));
    q = fma2(q, f, splat2(1.0f));
    v2u zb = __builtin_bit_cast(v2u, z);
    v2u sb = (zb << 23) + 0x3F800000u;   // 2^n bits (valid for n in [-127,127])
    return q * __builtin_bit_cast(v2f, sb);
}

struct __align__(16) WTile { float sx[64], sy[64], h[64], w[64]; };
struct Rows { float sx[4], sy[4], h[4], w[4]; };

// transform one raw (birth,death) strip column into this wave's SoA tile
__device__ __forceinline__ void stage_strip(WTile* T, const float2* src,
                                            int col0, int lane) {
    float2 bd = src[col0 + lane];
    float x = bd.x, l = bd.y - bd.x;
    T->sx[lane] = SQRT2C_F * x;
    T->sy[lane] = SQRT2C_F * l;
    T->h[lane]  = -LOG2E_F * fmaf(x, x, l * l);
    T->w[lane]  = l;
}

__device__ __forceinline__ void load_rows(Rows& R, const float2* src, int tid) {
    #pragma unroll
    for (int r = 0; r < 4; ++r) {
        float2 bd = src[r * 256 + tid];
        float x = bd.x, l = bd.y - bd.x;
        R.sx[r] = SQRT2C_F * x;
        R.sy[r] = SQRT2C_F * l;
        R.h[r]  = -LOG2E_F * fmaf(x, x, l * l);
        R.w[r]  = l;
    }
}

// full 64-col strip for rows r = RS..3
template<int RS>
__device__ __forceinline__ void strip_full(const WTile* T, const Rows& R,
                                           v2f* __restrict__ acc) {
    #pragma unroll 4
    for (int m = 0; m < 64; m += 2) {
        v2f psx = *(const v2f*)&T->sx[m];
        v2f psy = *(const v2f*)&T->sy[m];
        v2f ph  = *(const v2f*)&T->h[m];
        v2f pw  = *(const v2f*)&T->w[m];
        #pragma unroll
        for (int r = RS; r < 4; ++r) {
            v2f t = fma2(splat2(R.sx[r]), psx,
                     fma2(splat2(R.sy[r]), psy, ph + splat2(R.h[r])));
            acc[r] = fma2(exp2_poly(t), pw, acc[r]);
        }
    }
}

// diagonal 64x64 block for row r = RD: cols m < kcap (kcap = lane)
template<int RD>
__device__ __forceinline__ void strip_diag(const WTile* T, const Rows& R,
                                           int kcap, v2f* __restrict__ acc) {
    #pragma unroll 4
    for (int m = 0; m < 64; m += 2) {
        v2f psx = *(const v2f*)&T->sx[m];
        v2f psy = *(const v2f*)&T->sy[m];
        v2f ph  = *(const v2f*)&T->h[m];
        v2f pw  = *(const v2f*)&T->w[m];
        v2f wm = { (m     < kcap) ? pw.x : 0.0f,
                   (m + 1 < kcap) ? pw.y : 0.0f };
        v2f t = fma2(splat2(R.sx[RD]), psx,
                 fma2(splat2(R.sy[RD]), psy, ph + splat2(R.h[RD])));
        acc[RD] = fma2(exp2_poly(t), wm, acc[RD]);
    }
}

// one 64-col strip j of a symmetric term; row-block of row r is rb = 4r + w
__device__ __forceinline__ void do_strip_sym(const WTile* T, int j, int w,
                                             int kcap, const Rows& R,
                                             v2f* __restrict__ acc) {
    int d = j + 1 - w;
    int rstart = (d <= 0) ? 0 : ((d + 3) >> 2);
    switch (rstart) {                 // wave-uniform
        case 0: strip_full<0>(T, R, acc); break;
        case 1: strip_full<1>(T, R, acc); break;
        case 2: strip_full<2>(T, R, acc); break;
        case 3: strip_full<3>(T, R, acc); break;
        default: break;
    }
    int jd = j - w;
    if (jd >= 0 && jd < 16 && (jd & 3) == 0) {
        switch (jd >> 2) {            // wave-uniform
            case 0: strip_diag<0>(T, R, kcap, acc); break;
            case 1: strip_diag<1>(T, R, kcap, acc); break;
            case 2: strip_diag<2>(T, R, kcap, acc); break;
            case 3: strip_diag<3>(T, R, kcap, acc); break;
        }
    }
}

// ---------------- main (fixed shape N=M=1024) ----------------
// part 0..7:  XX sym strips {p,15-p};  8..15: YY sym;  16..31: XY strip p-16
__global__ __launch_bounds__(TPB) void mmd_main(
    const float* __restrict__ X, const float* __restrict__ Y,
    const float* __restrict__ weights, const float* __restrict__ ns,
    double* __restrict__ slots) {

    const int b    = blockIdx.y;
    const int part = blockIdx.x;
    const int tid  = threadIdx.x;
    const int w    = tid >> 6;
    const int lane = tid & 63;

    __shared__ WTile tiles[4];        // wave-private SoA tiles
    __shared__ double redbuf[4];
    WTile* T = &tiles[w];

    const float2* Xb = (const float2*)X + (size_t)b * 1024;
    const float2* Yb = (const float2*)Y + (size_t)b * 1024;

    float thread_val = 0.0f;
    v2f acc[4] = { splat2(0.0f), splat2(0.0f), splat2(0.0f), splat2(0.0f) };

    if (part < 16) {
        // symmetric term: strict lower triangle, strips {p, 15-p}
        const int p = part & 7;
        const float2* src = (part < 8) ? Xb : Yb;
        Rows R; load_rows(R, src, tid);

        stage_strip(T, src, p * 64, lane);          // within-wave DS order
        do_strip_sym(T, p, w, lane, R, acc);
        stage_strip(T, src, (15 - p) * 64, lane);
        do_strip_sym(T, 15 - p, w, lane, R, acc);

        float tv = 0.0f;
        #pragma unroll
        for (int r = 0; r < 4; ++r) tv = fmaf(R.w[r], acc[r].x + acc[r].y, tv);
        tv *= 2.0f;                                 // off-diagonal doubling
        if (p == 0) {                               // diagonal K=1: + sum w^2
            #pragma unroll
            for (int r = 0; r < 4; ++r) tv = fmaf(R.w[r], R.w[r], tv);
        }
        thread_val = tv;
    } else {
        // XY rectangle (sign -2), one 64-col strip of Y
        const int sp = part - 16;
        Rows R; load_rows(R, Xb, tid);
        stage_strip(T, Yb, sp * 64, lane);
        strip_full<0>(T, R, acc);
        float tv = 0.0f;
        #pragma unroll
        for (int r = 0; r < 4; ++r) tv = fmaf(R.w[r], acc[r].x + acc[r].y, tv);
        thread_val = -2.0f * tv;
    }

    // ---- block reduction in double; private slot (no atomics) ----
    double v = (double)thread_val;
    #pragma unroll
    for (int off = 32; off > 0; off >>= 1) v += __shfl_down(v, off, 64);
    if (lane == 0) redbuf[w] = v;
    __syncthreads();
    if (tid == 0) {
        double tot = (redbuf[0] + redbuf[1]) + (redbuf[2] + redbuf[3]);
        double nsb = (double)ns[b];
        slots[(size_t)b * 32 + part] = tot * ((double)weights[b] / (nsb * nsb));
    }
}

// deterministic sum of the per-block slots
__global__ void finalize_slots(const double* __restrict__ slots, int count,
                               float* __restrict__ out) {
    const int tid = threadIdx.x;
    double s = 0.0;
    for (int i = tid; i < count; i += TPB) s += slots[i];
    #pragma unroll
    for (int off = 32; off > 0; off >>= 1) s += __shfl_down(s, off, 64);
    __shared__ double redbuf[4];
    if ((tid & 63) == 0) redbuf[tid >> 6] = s;
    __syncthreads();
    if (tid == 0)
        out[0] = (float)((redbuf[0] + redbuf[1]) + (redbuf[2] + redbuf[3]));
}

// ---------------- generic fallback for unexpected shapes ----------------
struct __align__(16) P4 { float sx, sy, h, w; };
#define NSLOT 64
#define PTS_OFF 16400

__global__ void prep_kernel(const float* __restrict__ X, const float* __restrict__ Y,
                            P4* __restrict__ PX, P4* __restrict__ PY,
                            int nx_total, int ny_total, double* __restrict__ acc) {
    int i = blockIdx.x * blockDim.x + threadIdx.x;
    if (i < NSLOT) acc[i] = 0.0;
    if (i < nx_total) {
        float2 bd = ((const float2*)X)[i];
        float x = bd.x, l = bd.y - bd.x;
        P4 p; p.sx = SQRT2C_F * x; p.sy = SQRT2C_F * l;
        p.h = -LOG2E_F * fmaf(x, x, l * l); p.w = l;
        PX[i] = p;
    }
    if (i < ny_total) {
        float2 bd = ((const float2*)Y)[i];
        float x = bd.x, l = bd.y - bd.x;
        P4 p; p.sx = SQRT2C_F * x; p.sy = SQRT2C_F * l;
        p.h = -LOG2E_F * fmaf(x, x, l * l); p.w = l;
        PY[i] = p;
    }
}

__global__ __launch_bounds__(TPB) void mmd_generic(
    const P4* __restrict__ PXall, const P4* __restrict__ PYall,
    const float* __restrict__ weights, const float* __restrict__ ns,
    int N, int M, double* __restrict__ acc) {

    const int b    = blockIdx.z;
    const int term = blockIdx.y;
    const int seg  = blockIdx.x;

    const P4* __restrict__ A  = (term == 2) ? (PYall + (size_t)b * M) : (PXall + (size_t)b * N);
    const P4* __restrict__ Bp = (term == 0) ? (PXall + (size_t)b * N) : (PYall + (size_t)b * M);
    const int nrows = (term == 2) ? M : N;
    const int mlen  = (term == 0) ? N : M;
    const float sign = (term == 1) ? -2.0f : 1.0f;

    const int mstart = seg * 32;
    const int cnt = (mstart + 32 <= mlen) ? 32 : (mlen > mstart ? mlen - mstart : 0);

    __shared__ P4 tile[32];
    __shared__ double redbuf[TPB / 64];
    if (threadIdx.x < cnt) tile[threadIdx.x] = Bp[mstart + threadIdx.x];
    __syncthreads();

    float thread_val = 0.0f;
    for (int n = threadIdx.x; n < nrows; n += TPB) {
        P4 a = A[n];
        float ss = 0.0f;
        for (int m = 0; m < cnt; ++m) {
            P4 p = tile[m];
            float t = fmaf(a.sx, p.sx, fmaf(a.sy, p.sy, a.h + p.h));
            ss = fmaf(__builtin_amdgcn_exp2f(t), p.w, ss);
        }
        thread_val = fmaf(a.w, ss, thread_val);
    }

    double v = (double)thread_val;
    #pragma unroll
    for (int off = 32; off > 0; off >>= 1) v += __shfl_down(v, off, 64);
    if ((threadIdx.x & 63) == 0) redbuf[threadIdx.x >> 6] = v;
    __syncthreads();
    if (threadIdx.x == 0) {
        double tot = (redbuf[0] + redbuf[1]) + (redbuf[2] + redbuf[3]);
        double nsb = (double)ns[b];
        atomicAdd(&acc[b], (double)sign * tot * ((double)weights[b] / (nsb * nsb)));
    }
}

extern "C" void kernel_launch(void* const* d_in, const int* in_sizes, int n_in,
                              void* d_out, int out_size, void* d_ws, size_t ws_size,
                              hipStream_t stream) {
    const float* X  = (const float*)d_in[0];
    const float* Y  = (const float*)d_in[1];
    const float* W  = (const float*)d_in[2];
    const float* NS = (const float*)d_in[3];

    const int B = in_sizes[2];
    const int N = in_sizes[0] / (2 * B);
    const int M = in_sizes[1] / (2 * B);

    if (N == 1024 && M == 1024 && B * 32 * 8 <= 16384) {
        double* slots = (double*)d_ws;              // B*32 doubles, all rewritten
        dim3 grid(32, B);
        mmd_main<<<grid, TPB, 0, stream>>>(X, Y, W, NS, slots);
        finalize_slots<<<1, TPB, 0, stream>>>(slots, B * 32, (float*)d_out);
    } else {
        double* acc = (double*)d_ws;
        P4* PX = (P4*)((char*)d_ws + PTS_OFF);
        P4* PY = PX + (size_t)B * N;
        const int nx_total = B * N, ny_total = B * M;
        const int prep_total = nx_total > ny_total ? nx_total : ny_total;
        prep_kernel<<<(prep_total + 255) / 256, 256, 0, stream>>>(
            X, Y, PX, PY, nx_total, ny_total, acc);
        const int mlen_max = N > M ? N : M;
        dim3 grid((mlen_max + 31) / 32, 3, B);
        mmd_generic<<<grid, TPB, 0, stream>>>(PX, PY, W, NS, N, M, acc);
        finalize_slots<<<1, TPB, 0, stream>>>(acc, NSLOT, (float*)d_out);
    }
}

// Round 7
// 85.957 us; speedup vs baseline: 1.3485x; 1.3485x over previous
//
#include <hip/hip_runtime.h>

// MMD over persistence diagrams, RBF kernel, WIDTH=1, DECAY=1.
// out = sum_b weights[b]/ns[b]^2 * (S_XX - 2 S_XY + S_YY)
// S_AB = sum_{n,m} exp(-||a_n-b_m||^2) * wa_n * wb_m,
// points (birth,death)->(x=birth, l=death-birth), w = l.
//
// R7 = R5 (best: trans v_exp, sym-triangle, 2048 blocks, wave-private
// tiles, no hot barriers) + in-block transform (no prep kernel) +
// row-constant factored out of exp: exp2(dot+ah+ph) = exp2(ah)*exp2(dot+ph)
// -> inner loop is 2 FMA + exp + acc-FMA per pair. Slot-store reduction
// (no atomics), deterministic finalize.
// NOTE (R6 lesson): v_pk_fma_f32 is NOT a throughput doubler on gfx950
// (FP32 peak = scalar rate); polynomial exp2 regressed 2.2x. Keep v_exp.

#define LOG2E_F  1.44269504088896340736f
#define SQRT2C_F 1.69864360213614f     // sqrt(2*log2(e))

#define TPB 256

struct __align__(16) P4 { float sx, sy, h, w; };
struct Rows { float sx[4], sy[4], cw[4], w[4]; };  // cw = w * exp2(h)

// transform one raw (birth,death) strip column into this wave's tile
__device__ __forceinline__ void stage_strip(P4* tile, const float2* src,
                                            int col0, int lane) {
    float2 bd = src[col0 + lane];
    float x = bd.x, l = bd.y - bd.x;
    P4 p;
    p.sx = SQRT2C_F * x;
    p.sy = SQRT2C_F * l;
    p.h  = -LOG2E_F * fmaf(x, x, l * l);
    p.w  = l;
    tile[lane] = p;
}

__device__ __forceinline__ void load_rows(Rows& R, const float2* src, int tid) {
    #pragma unroll
    for (int r = 0; r < 4; ++r) {
        float2 bd = src[r * 256 + tid];
        float x = bd.x, l = bd.y - bd.x;
        R.sx[r] = SQRT2C_F * x;
        R.sy[r] = SQRT2C_F * l;
        float h = -LOG2E_F * fmaf(x, x, l * l);
        R.cw[r] = l * __builtin_amdgcn_exp2f(h);   // folded row scale
        R.w[r]  = l;
    }
}

// full 64-col strip for rows r = RS..3 (all 64 cols active)
template<int RS>
__device__ __forceinline__ void strip_full(const P4* __restrict__ tile,
                                           const Rows& R, float* __restrict__ s) {
    #pragma unroll 4
    for (int m = 0; m < 64; ++m) {
        P4 p = tile[m];
        #pragma unroll
        for (int r = RS; r < 4; ++r) {
            float t = fmaf(R.sx[r], p.sx, fmaf(R.sy[r], p.sy, p.h));
            s[r] = fmaf(__builtin_amdgcn_exp2f(t), p.w, s[r]);
        }
    }
}

// diagonal 64x64 block for row r = RD: cols m < kcap (kcap = lane)
template<int RD>
__device__ __forceinline__ void strip_diag(const P4* __restrict__ tile, int kcap,
                                           const Rows& R, float* __restrict__ s) {
    #pragma unroll 4
    for (int m = 0; m < 64; ++m) {
        P4 p = tile[m];
        float wsel = (m < kcap) ? p.w : 0.0f;
        float t = fmaf(R.sx[RD], p.sx, fmaf(R.sy[RD], p.sy, p.h));
        s[RD] = fmaf(__builtin_amdgcn_exp2f(t), wsel, s[RD]);
    }
}

// one 64-col strip j of a symmetric term; row-block of row r is rb = 4r + w
__device__ __forceinline__ void do_strip_sym(const P4* __restrict__ tile, int j, int w,
                                             int kcap, const Rows& R,
                                             float* __restrict__ s) {
    int d = j + 1 - w;
    int rstart = (d <= 0) ? 0 : ((d + 3) >> 2);
    switch (rstart) {                 // wave-uniform
        case 0: strip_full<0>(tile, R, s); break;
        case 1: strip_full<1>(tile, R, s); break;
        case 2: strip_full<2>(tile, R, s); break;
        case 3: strip_full<3>(tile, R, s); break;
        default: break;
    }
    int jd = j - w;
    if (jd >= 0 && jd < 16 && (jd & 3) == 0) {
        switch (jd >> 2) {            // wave-uniform
            case 0: strip_diag<0>(tile, kcap, R, s); break;
            case 1: strip_diag<1>(tile, kcap, R, s); break;
            case 2: strip_diag<2>(tile, kcap, R, s); break;
            case 3: strip_diag<3>(tile, kcap, R, s); break;
        }
    }
}

// ---------------- main (fixed shape N=M=1024) ----------------
// part 0..7:  XX sym strips {p,15-p};  8..15: YY sym;  16..31: XY strip p-16
__global__ __launch_bounds__(TPB) void mmd_main(
    const float* __restrict__ X, const float* __restrict__ Y,
    const float* __restrict__ weights, const float* __restrict__ ns,
    double* __restrict__ slots) {

    const int b    = blockIdx.y;
    const int part = blockIdx.x;
    const int tid  = threadIdx.x;
    const int w    = tid >> 6;
    const int lane = tid & 63;

    __shared__ P4 tiles[4][64];       // wave-private tiles (identical data; no barriers)
    __shared__ double redbuf[4];
    P4* tile = tiles[w];

    const float2* Xb = (const float2*)X + (size_t)b * 1024;
    const float2* Yb = (const float2*)Y + (size_t)b * 1024;

    float thread_val = 0.0f;

    if (part < 16) {
        // symmetric term: strict lower triangle, strips {p, 15-p}, doubled + diag
        const int p = part & 7;
        const float2* src = (part < 8) ? Xb : Yb;
        Rows R; load_rows(R, src, tid);
        float s[4] = {0.0f, 0.0f, 0.0f, 0.0f};

        stage_strip(tile, src, p * 64, lane);       // within-wave DS order: no barrier
        do_strip_sym(tile, p, w, lane, R, s);
        stage_strip(tile, src, (15 - p) * 64, lane);
        do_strip_sym(tile, 15 - p, w, lane, R, s);

        float tv = 0.0f;
        #pragma unroll
        for (int r = 0; r < 4; ++r) tv = fmaf(R.cw[r], s[r], tv);
        tv *= 2.0f;                                 // off-diagonal doubling
        if (p == 0) {                               // diagonal K=1: + sum w^2
            #pragma unroll
            for (int r = 0; r < 4; ++r) tv = fmaf(R.w[r], R.w[r], tv);
        }
        thread_val = tv;
    } else {
        // XY rectangle (sign -2), one 64-col strip of Y
        const int sp = part - 16;
        Rows R; load_rows(R, Xb, tid);
        float s[4] = {0.0f, 0.0f, 0.0f, 0.0f};
        stage_strip(tile, Yb, sp * 64, lane);
        strip_full<0>(tile, R, s);
        float tv = 0.0f;
        #pragma unroll
        for (int r = 0; r < 4; ++r) tv = fmaf(R.cw[r], s[r], tv);
        thread_val = -2.0f * tv;
    }

    // ---- block reduction in double; private slot (no atomics) ----
    double v = (double)thread_val;
    #pragma unroll
    for (int off = 32; off > 0; off >>= 1) v += __shfl_down(v, off, 64);
    if (lane == 0) redbuf[w] = v;
    __syncthreads();
    if (tid == 0) {
        double tot = (redbuf[0] + redbuf[1]) + (redbuf[2] + redbuf[3]);
        double nsb = (double)ns[b];
        slots[(size_t)b * 32 + part] = tot * ((double)weights[b] / (nsb * nsb));
    }
}

// deterministic sum of the per-block slots
__global__ void finalize_slots(const double* __restrict__ slots, int count,
                               float* __restrict__ out) {
    const int tid = threadIdx.x;
    double s = 0.0;
    for (int i = tid; i < count; i += TPB) s += slots[i];
    #pragma unroll
    for (int off = 32; off > 0; off >>= 1) s += __shfl_down(s, off, 64);
    __shared__ double redbuf[4];
    if ((tid & 63) == 0) redbuf[tid >> 6] = s;
    __syncthreads();
    if (tid == 0)
        out[0] = (float)((redbuf[0] + redbuf[1]) + (redbuf[2] + redbuf[3]));
}

// ---------------- generic fallback for unexpected shapes ----------------
#define NSLOT 64
#define PTS_OFF 16400

__global__ void prep_kernel(const float* __restrict__ X, const float* __restrict__ Y,
                            P4* __restrict__ PX, P4* __restrict__ PY,
                            int nx_total, int ny_total, double* __restrict__ acc) {
    int i = blockIdx.x * blockDim.x + threadIdx.x;
    if (i < NSLOT) acc[i] = 0.0;
    if (i < nx_total) {
        float2 bd = ((const float2*)X)[i];
        float x = bd.x, l = bd.y - bd.x;
        P4 p; p.sx = SQRT2C_F * x; p.sy = SQRT2C_F * l;
        p.h = -LOG2E_F * fmaf(x, x, l * l); p.w = l;
        PX[i] = p;
    }
    if (i < ny_total) {
        float2 bd = ((const float2*)Y)[i];
        float x = bd.x, l = bd.y - bd.x;
        P4 p; p.sx = SQRT2C_F * x; p.sy = SQRT2C_F * l;
        p.h = -LOG2E_F * fmaf(x, x, l * l); p.w = l;
        PY[i] = p;
    }
}

__global__ __launch_bounds__(TPB) void mmd_generic(
    const P4* __restrict__ PXall, const P4* __restrict__ PYall,
    const float* __restrict__ weights, const float* __restrict__ ns,
    int N, int M, double* __restrict__ acc) {

    const int b    = blockIdx.z;
    const int term = blockIdx.y;
    const int seg  = blockIdx.x;

    const P4* __restrict__ A  = (term == 2) ? (PYall + (size_t)b * M) : (PXall + (size_t)b * N);
    const P4* __restrict__ Bp = (term == 0) ? (PXall + (size_t)b * N) : (PYall + (size_t)b * M);
    const int nrows = (term == 2) ? M : N;
    const int mlen  = (term == 0) ? N : M;
    const float sign = (term == 1) ? -2.0f : 1.0f;

    const int mstart = seg * 32;
    const int cnt = (mstart + 32 <= mlen) ? 32 : (mlen > mstart ? mlen - mstart : 0);

    __shared__ P4 tile[32];
    __shared__ double redbuf[TPB / 64];
    if (threadIdx.x < cnt) tile[threadIdx.x] = Bp[mstart + threadIdx.x];
    __syncthreads();

    float thread_val = 0.0f;
    for (int n = threadIdx.x; n < nrows; n += TPB) {
        P4 a = A[n];
        float ss = 0.0f;
        for (int m = 0; m < cnt; ++m) {
            P4 p = tile[m];
            float t = fmaf(a.sx, p.sx, fmaf(a.sy, p.sy, a.h + p.h));
            ss = fmaf(__builtin_amdgcn_exp2f(t), p.w, ss);
        }
        thread_val = fmaf(a.w, ss, thread_val);
    }

    double v = (double)thread_val;
    #pragma unroll
    for (int off = 32; off > 0; off >>= 1) v += __shfl_down(v, off, 64);
    if ((threadIdx.x & 63) == 0) redbuf[threadIdx.x >> 6] = v;
    __syncthreads();
    if (threadIdx.x == 0) {
        double tot = (redbuf[0] + redbuf[1]) + (redbuf[2] + redbuf[3]);
        double nsb = (double)ns[b];
        atomicAdd(&acc[b], (double)sign * tot * ((double)weights[b] / (nsb * nsb)));
    }
}

extern "C" void kernel_launch(void* const* d_in, const int* in_sizes, int n_in,
                              void* d_out, int out_size, void* d_ws, size_t ws_size,
                              hipStream_t stream) {
    const float* X  = (const float*)d_in[0];
    const float* Y  = (const float*)d_in[1];
    const float* W  = (const float*)d_in[2];
    const float* NS = (const float*)d_in[3];

    const int B = in_sizes[2];
    const int N = in_sizes[0] / (2 * B);
    const int M = in_sizes[1] / (2 * B);

    if (N == 1024 && M == 1024 && (size_t)B * 32 * 8 <= ws_size) {
        double* slots = (double*)d_ws;              // B*32 doubles, all rewritten
        dim3 grid(32, B);
        mmd_main<<<grid, TPB, 0, stream>>>(X, Y, W, NS, slots);
        finalize_slots<<<1, TPB, 0, stream>>>(slots, B * 32, (float*)d_out);
    } else {
        double* acc = (double*)d_ws;
        P4* PX = (P4*)((char*)d_ws + PTS_OFF);
        P4* PY = PX + (size_t)B * N;
        const int nx_total = B * N, ny_total = B * M;
        const int prep_total = nx_total > ny_total ? nx_total : ny_total;
        prep_kernel<<<(prep_total + 255) / 256, 256, 0, stream>>>(
            X, Y, PX, PY, nx_total, ny_total, acc);
        const int mlen_max = N > M ? N : M;
        dim3 grid((mlen_max + 31) / 32, 3, B);
        mmd_generic<<<grid, TPB, 0, stream>>>(PX, PY, W, NS, N, M, acc);
        finalize_slots<<<1, TPB, 0, stream>>>(acc, NSLOT, (float*)d_out);
    }
}